// Round 5
// baseline (564.054 us; speedup 1.0000x reference)
//
#include <hip/hip_runtime.h>
#include <math.h>

// ---- d_ws layout (float indices) ----
#define WS_R    0      // R[2][20] rel factors
#define WS_HW   40     // hid_W[20][20]
#define WS_HB   440    // hid_b[20]
#define WS_MW   460    // merge_W[20]
#define WS_MB   480    // merge_b
#define WS_B0   482    // base[2][16]
#define WS_Z0   514    // zvec[2][16]
#define WS_W4   546    // lane_W[:, :4] as [h][k] : 64
#define WS_DW   610    // d_W[4]
#define WS_DB   614    // d_b[4]
#define WS_WU   618    // Wu[20][16]
#define WS_WV   938    // Wv[20][16]
#define WS_UB   1258   // lane_conv_b[20]
#define WS_PM   1278   // int pmask[8]
// total 1286 floats

__global__ void frap_setup(
    const int* __restrict__ p2m, const int* __restrict__ comp_mask,
    const float* __restrict__ p_emb, const float* __restrict__ d_W, const float* __restrict__ d_b,
    const float* __restrict__ lane_W, const float* __restrict__ lane_b,
    const float* __restrict__ lane_conv_W, const float* __restrict__ lane_conv_b,
    const float* __restrict__ rel_emb, const float* __restrict__ rel_conv_W, const float* __restrict__ rel_conv_b,
    const float* __restrict__ hid_W, const float* __restrict__ hid_b,
    const float* __restrict__ merge_W, const float* __restrict__ merge_b,
    float* __restrict__ ws)
{
    const int t = threadIdx.x;
    const int NTH = 256;
    for (int i = t; i < 40; i += NTH) {
        int c = i / 20, o = i % 20;
        float s = rel_conv_b[o];
        #pragma unroll
        for (int k = 0; k < 4; ++k)
            s = fmaf(rel_conv_W[o*4+k], fmaxf(rel_emb[c*4+k], 0.f), s);
        ws[WS_R + i] = fmaxf(s, 0.f);
    }
    for (int i = t; i < 400; i += NTH) ws[WS_HW + i] = hid_W[i];
    for (int i = t; i < 20; i += NTH) {
        ws[WS_HB + i] = hid_b[i];
        ws[WS_MW + i] = merge_W[i];
        ws[WS_UB + i] = lane_conv_b[i];
    }
    if (t == 0) ws[WS_MB] = merge_b[0];
    for (int i = t; i < 32; i += NTH) {
        int c = i >> 4, h = i & 15;
        float s = lane_b[h];
        #pragma unroll
        for (int k = 0; k < 4; ++k) {
            float sg = 1.f/(1.f + __expf(-p_emb[c*4+k]));
            s = fmaf(lane_W[h*8+4+k], sg, s);
        }
        ws[WS_B0 + c*16 + h] = s;              // base_c[h]
        float z = s;
        #pragma unroll
        for (int k = 0; k < 4; ++k) {
            float sg = 1.f/(1.f + __expf(-d_b[k]));
            z = fmaf(lane_W[h*8+k], sg, z);
        }
        ws[WS_Z0 + c*16 + h] = fmaxf(z, 0.f);  // zvec_c[h]
    }
    for (int i = t; i < 64; i += NTH) ws[WS_W4 + i] = lane_W[(i>>2)*8 + (i&3)];
    if (t < 4) { ws[WS_DW + t] = d_W[t]; ws[WS_DB + t] = d_b[t]; }
    for (int i = t; i < 320; i += NTH) {
        int o = i >> 4, h = i & 15;
        ws[WS_WU + i] = lane_conv_W[o*32 + h];
        ws[WS_WV + i] = lane_conv_W[o*32 + 16 + h];
    }
    int* wi = (int*)ws;
    for (int i = t; i < 8; i += NTH) {
        int mk = 0;
        for (int m = 0; m < 12; ++m) mk |= (p2m[i*12 + m] & 1) << m;
        wi[WS_PM + i] = mk;
    }
}

__global__ __launch_bounds__(512, 4) void frap_main(
    const float* __restrict__ states, const int* __restrict__ comp_mask,
    const float* __restrict__ ws, float* __restrict__ out, int B)
{
    // v[(p*64+lane)*20 + o]: per-thread contiguous 80B, float4 rw, 0 conflicts (measured r3)
    __shared__ float v_s[8*64*20];                 // 40,960 B
    const int tid  = threadIdx.x;
    const int lane = tid & 63;
    const int p    = __builtin_amdgcn_readfirstlane(tid >> 6);  // wave-uniform phase
    const int b    = blockIdx.x * 64 + lane;
    const int bc   = b < B ? b : B - 1;
    const int* wi  = (const int*)ws;

    const float* srow = states + (size_t)bc * 13;
    const int cmask = wi[WS_PM + (int)srow[0]];    // lane-varying
    float dm[12];
    #pragma unroll
    for (int m = 0; m < 12; ++m) dm[m] = srow[1+m];

    const int pmask = wi[WS_PM + p];               // scalar

    // ---- stage 1: agg[16]; unconnected movements folded into init
    const int notp = ~pmask & 0xFFF;
    const float cnt1 = (float)__popc(cmask & notp);
    const float cnt0 = (float)__popc(~cmask & notp);

    float agg[16];
    #pragma unroll
    for (int h = 0; h < 16; ++h)
        agg[h] = fmaf(cnt0, ws[WS_Z0+h], cnt1 * ws[WS_Z0+16+h]);

    #pragma unroll
    for (int m = 0; m < 12; ++m) {
        if ((pmask >> m) & 1) {                    // wave-uniform branch
            const bool cbit = (cmask >> m) & 1;
            float e[4];
            #pragma unroll
            for (int k = 0; k < 4; ++k) {
                float xx = fmaf(dm[m], ws[WS_DW+k], ws[WS_DB+k]);
                e[k] = __builtin_amdgcn_rcpf(1.f + __expf(-xx));
            }
            #pragma unroll
            for (int h = 0; h < 16; ++h) {
                float t = cbit ? ws[WS_B0+16+h] : ws[WS_B0+h];
                #pragma unroll
                for (int k = 0; k < 4; ++k)
                    t = fmaf(ws[WS_W4 + h*4 + k], e[k], t);
                agg[h] += fmaxf(t, 0.f);
            }
        }
    }

    // ---- stage 2: u (regs) + v (LDS, float4 writes)
    float u[20], sv[20];
    #pragma unroll
    for (int o = 0; o < 20; ++o) {
        float su = ws[WS_UB + o];
        float s2 = 0.f;
        #pragma unroll
        for (int h = 0; h < 16; ++h) {
            su = fmaf(ws[WS_WU + o*16 + h], agg[h], su);
            s2 = fmaf(ws[WS_WV + o*16 + h], agg[h], s2);
        }
        u[o]  = su;
        sv[o] = s2;
    }
    {
        float* vdst = &v_s[(p*64 + lane)*20];
        #pragma unroll
        for (int o = 0; o < 20; o += 4) {
            float4 t4; t4.x = sv[o]; t4.y = sv[o+1]; t4.z = sv[o+2]; t4.w = sv[o+3];
            *(float4*)(vdst + o) = t4;
        }
    }
    __syncthreads();

    // ---- stage 3: y = relu(u+v_j)*R_cf ; s = hid_W·y ; q += mw·relu(s)
    // hid_W is 1.6 KB shared by every wave -> sK$-resident s_load stream.
    float q_acc = 7.f * ws[WS_MB];
    for (int qi = 0; qi < 7; ++qi) {
        const int j  = qi + (qi >= p ? 1 : 0);              // scalar
        const int cf = comp_mask[p*7 + qi];                 // scalar
        const float* Rc = ws + WS_R + cf*20;                // scalar ptr, K$-hit
        const float* vj = &v_s[(j*64 + lane)*20];
        float y[20];
        #pragma unroll
        for (int o = 0; o < 20; o += 4) {
            float4 t4 = *(const float4*)(vj + o);
            y[o]   = fmaxf(u[o]   + t4.x, 0.f) * Rc[o];
            y[o+1] = fmaxf(u[o+1] + t4.y, 0.f) * Rc[o+1];
            y[o+2] = fmaxf(u[o+2] + t4.z, 0.f) * Rc[o+2];
            y[o+3] = fmaxf(u[o+3] + t4.w, 0.f) * Rc[o+3];
        }
        #pragma unroll
        for (int o2 = 0; o2 < 20; ++o2) {
            float s = ws[WS_HB + o2];
            #pragma unroll
            for (int o = 0; o < 20; ++o)
                s = fmaf(ws[WS_HW + o2*20 + o], y[o], s);
            q_acc = fmaf(ws[WS_MW + o2], fmaxf(s, 0.f), q_acc);
        }
    }
    if (b < B) out[(size_t)b*8 + p] = q_acc;
}

extern "C" void kernel_launch(void* const* d_in, const int* in_sizes, int n_in,
                              void* d_out, int out_size, void* d_ws, size_t ws_size,
                              hipStream_t stream) {
    const float* states       = (const float*)d_in[0];
    const int*   p2m          = (const int*)  d_in[1];
    const int*   comp_mask    = (const int*)  d_in[3];
    const float* p_emb        = (const float*)d_in[4];
    const float* d_W          = (const float*)d_in[5];
    const float* d_b          = (const float*)d_in[6];
    const float* lane_W       = (const float*)d_in[7];
    const float* lane_b       = (const float*)d_in[8];
    const float* lane_conv_W  = (const float*)d_in[9];
    const float* lane_conv_b  = (const float*)d_in[10];
    const float* rel_emb      = (const float*)d_in[11];
    const float* rel_conv_W   = (const float*)d_in[12];
    const float* rel_conv_b   = (const float*)d_in[13];
    const float* hid_W        = (const float*)d_in[14];
    const float* hid_b        = (const float*)d_in[15];
    const float* merge_W      = (const float*)d_in[16];
    const float* merge_b      = (const float*)d_in[17];
    float* out = (float*)d_out;
    float* ws  = (float*)d_ws;

    frap_setup<<<1, 256, 0, stream>>>(p2m, comp_mask, p_emb, d_W, d_b, lane_W, lane_b,
        lane_conv_W, lane_conv_b, rel_emb, rel_conv_W, rel_conv_b, hid_W, hid_b,
        merge_W, merge_b, ws);

    int B = in_sizes[0] / 13;
    int grid = (B + 63) / 64;
    frap_main<<<grid, 512, 0, stream>>>(states, comp_mask, ws, out, B);
}

// Round 6
// 67.349 us; speedup vs baseline: 8.3751x; 8.3751x over previous
//
#include <hip/hip_runtime.h>
#include <math.h>

typedef _Float16 h2 __attribute__((ext_vector_type(2)));
typedef unsigned int uint32;

// ---- d_ws layout (float indices) ----
#define WS_HB 0      // hid_b[20]
#define WS_MW 20     // merge_W[20]
#define WS_MB 40     // merge_b
#define WS_B0 44     // base[2][16]
#define WS_Z0 76     // zvec[2][16]
#define WS_W4 108    // lane_W[:, :4] as [h][k] : 64
#define WS_DW 172    // d_W[4]
#define WS_DB 176    // d_b[4]
#define WS_WU 180    // Wu[20][16]
#define WS_WV 500    // Wv[20][16]
#define WS_UB 820    // lane_conv_b[20]
#define WS_PM 840    // int pmask[8]
#define WS_HH 848    // uint32 Hh[56][20][10]: f16-pair packed Hsel = 11200
// total 12048 floats = 48,192 B

__global__ void frap_setup(
    const int* __restrict__ p2m, const int* __restrict__ comp_mask,
    const float* __restrict__ p_emb, const float* __restrict__ d_W, const float* __restrict__ d_b,
    const float* __restrict__ lane_W, const float* __restrict__ lane_b,
    const float* __restrict__ lane_conv_W, const float* __restrict__ lane_conv_b,
    const float* __restrict__ rel_emb, const float* __restrict__ rel_conv_W, const float* __restrict__ rel_conv_b,
    const float* __restrict__ hid_W, const float* __restrict__ hid_b,
    const float* __restrict__ merge_W, const float* __restrict__ merge_b,
    float* __restrict__ ws)
{
    __shared__ float R[40];     // rel factors R[c][o]
    __shared__ float HW[400];   // hid_W
    const int t = threadIdx.x;
    const int NTH = 256;

    for (int i = t; i < 40; i += NTH) {
        int c = i / 20, o = i % 20;
        float s = rel_conv_b[o];
        #pragma unroll
        for (int k = 0; k < 4; ++k)
            s = fmaf(rel_conv_W[o*4+k], fmaxf(rel_emb[c*4+k], 0.f), s);
        R[i] = fmaxf(s, 0.f);
    }
    for (int i = t; i < 400; i += NTH) HW[i] = hid_W[i];
    __syncthreads();

    // Hh[pq][o2][j] = pack_f16( HW[o2][2j]*R[cf][2j], HW[o2][2j+1]*R[cf][2j+1] )
    uint32* Hh = (uint32*)ws + WS_HH;
    const int gstride = gridDim.x * blockDim.x;
    for (int e = blockIdx.x*blockDim.x + t; e < 56*200; e += gstride) {
        int j  = e % 10;
        int o2 = (e / 10) % 20;
        int pq = e / 200;
        int cf = comp_mask[pq];
        float a = HW[o2*20 + 2*j]     * R[cf*20 + 2*j];
        float b = HW[o2*20 + 2*j + 1] * R[cf*20 + 2*j + 1];
        _Float16 ha = (_Float16)a, hb = (_Float16)b;  // RTN converts
        Hh[e] = (uint32)__builtin_bit_cast(unsigned short, ha)
              | ((uint32)__builtin_bit_cast(unsigned short, hb) << 16);
    }
    if (blockIdx.x != 0) return;

    for (int i = t; i < 20; i += NTH) {
        ws[WS_HB + i] = hid_b[i];
        ws[WS_MW + i] = merge_W[i];
        ws[WS_UB + i] = lane_conv_b[i];
    }
    if (t == 0) ws[WS_MB] = merge_b[0];
    for (int i = t; i < 32; i += NTH) {
        int c = i >> 4, h = i & 15;
        float s = lane_b[h];
        #pragma unroll
        for (int k = 0; k < 4; ++k) {
            float sg = 1.f/(1.f + __expf(-p_emb[c*4+k]));
            s = fmaf(lane_W[h*8+4+k], sg, s);
        }
        ws[WS_B0 + c*16 + h] = s;              // base_c[h]
        float z = s;
        #pragma unroll
        for (int k = 0; k < 4; ++k) {
            float sg = 1.f/(1.f + __expf(-d_b[k]));
            z = fmaf(lane_W[h*8+k], sg, z);
        }
        ws[WS_Z0 + c*16 + h] = fmaxf(z, 0.f);  // zvec_c[h]
    }
    for (int i = t; i < 64; i += NTH) ws[WS_W4 + i] = lane_W[(i>>2)*8 + (i&3)];
    if (t < 4) { ws[WS_DW + t] = d_W[t]; ws[WS_DB + t] = d_b[t]; }
    for (int i = t; i < 320; i += NTH) {
        int o = i >> 4, h = i & 15;
        ws[WS_WU + i] = lane_conv_W[o*32 + h];
        ws[WS_WV + i] = lane_conv_W[o*32 + 16 + h];
    }
    int* wi = (int*)ws;
    for (int i = t; i < 8; i += NTH) {
        int mk = 0;
        for (int m = 0; m < 12; ++m) mk |= (p2m[i*12 + m] & 1) << m;
        wi[WS_PM + i] = mk;
    }
}

__global__ __launch_bounds__(512, 6) void frap_main(
    const float* __restrict__ states,
    const float* __restrict__ ws, float* __restrict__ out, int B)
{
    // v[(p*64+lane)*20 + o]: per-thread contiguous 80B, float4 rw, 0 conflicts (measured r3)
    __shared__ float v_s[8*64*20];                 // 40,960 B
    const int tid  = threadIdx.x;
    const int lane = tid & 63;
    const int p    = __builtin_amdgcn_readfirstlane(tid >> 6);  // wave-uniform phase
    const int b    = blockIdx.x * 64 + lane;
    const int bc   = b < B ? b : B - 1;
    const int* wi  = (const int*)ws;

    const float* srow = states + (size_t)bc * 13;
    const int cmask = wi[WS_PM + (int)srow[0]];    // lane-varying
    float dm[12];
    #pragma unroll
    for (int m = 0; m < 12; ++m) dm[m] = srow[1+m];

    const int pmask = wi[WS_PM + p];               // scalar

    // ---- stage 1: agg[16]; unconnected movements folded into init
    const int notp = ~pmask & 0xFFF;
    const float cnt1 = (float)__popc(cmask & notp);
    const float cnt0 = (float)__popc(~cmask & notp);

    float agg[16];
    #pragma unroll
    for (int h = 0; h < 16; ++h)
        agg[h] = fmaf(cnt0, ws[WS_Z0+h], cnt1 * ws[WS_Z0+16+h]);

    #pragma unroll
    for (int m = 0; m < 12; ++m) {
        if ((pmask >> m) & 1) {                    // wave-uniform branch
            const bool cbit = (cmask >> m) & 1;
            float e[4];
            #pragma unroll
            for (int k = 0; k < 4; ++k) {
                float xx = fmaf(dm[m], ws[WS_DW+k], ws[WS_DB+k]);
                e[k] = __builtin_amdgcn_rcpf(1.f + __expf(-xx));
            }
            #pragma unroll
            for (int h = 0; h < 16; ++h) {
                float t = cbit ? ws[WS_B0+16+h] : ws[WS_B0+h];
                #pragma unroll
                for (int k = 0; k < 4; ++k)
                    t = fmaf(ws[WS_W4 + h*4 + k], e[k], t);
                agg[h] += fmaxf(t, 0.f);
            }
        }
    }

    // ---- stage 2: u (regs) + v (LDS, float4 writes)
    float u[20], sv[20];
    #pragma unroll
    for (int o = 0; o < 20; ++o) {
        float su = ws[WS_UB + o];
        float s2 = 0.f;
        #pragma unroll
        for (int h = 0; h < 16; ++h) {
            su = fmaf(ws[WS_WU + o*16 + h], agg[h], su);
            s2 = fmaf(ws[WS_WV + o*16 + h], agg[h], s2);
        }
        u[o]  = su;
        sv[o] = s2;
    }
    {
        float* vdst = &v_s[(p*64 + lane)*20];
        #pragma unroll
        for (int o = 0; o < 20; o += 4) {
            float4 t4; t4.x = sv[o]; t4.y = sv[o+1]; t4.z = sv[o+2]; t4.w = sv[o+3];
            *(float4*)(vdst + o) = t4;
        }
    }
    __syncthreads();

    // ---- stage 3: y = relu(u+v_j); pack f16 pairs; s = Hh·y via v_dot2_f32_f16
    // Hh pointer is per-(p,qi) scalar and qi-VARYING -> clean s_load stream, no LICM bait.
    float q_acc = 7.f * ws[WS_MB];
    const uint32* Hq_base = (const uint32*)ws + WS_HH;
    for (int qi = 0; qi < 7; ++qi) {
        const int j = qi + (qi >= p ? 1 : 0);               // scalar
        const float* vj = &v_s[(j*64 + lane)*20];
        uint32 ypk[10];
        #pragma unroll
        for (int o = 0; o < 20; o += 4) {
            float4 t4 = *(const float4*)(vj + o);
            float y0 = fmaxf(u[o]   + t4.x, 0.f);
            float y1 = fmaxf(u[o+1] + t4.y, 0.f);
            float y2 = fmaxf(u[o+2] + t4.z, 0.f);
            float y3 = fmaxf(u[o+3] + t4.w, 0.f);
            ypk[o/2]     = __builtin_bit_cast(uint32, __builtin_amdgcn_cvt_pkrtz(y0, y1));
            ypk[o/2 + 1] = __builtin_bit_cast(uint32, __builtin_amdgcn_cvt_pkrtz(y2, y3));
        }
        const uint32* Hq = Hq_base + (p*7 + qi)*200;        // scalar ptr
        #pragma unroll
        for (int o2 = 0; o2 < 20; ++o2) {
            float s = ws[WS_HB + o2];
            #pragma unroll
            for (int jj = 0; jj < 10; ++jj)
                s = __builtin_amdgcn_fdot2(__builtin_bit_cast(h2, Hq[o2*10 + jj]),
                                           __builtin_bit_cast(h2, ypk[jj]), s, false);
            q_acc = fmaf(ws[WS_MW + o2], fmaxf(s, 0.f), q_acc);
        }
    }
    if (b < B) out[(size_t)b*8 + p] = q_acc;
}

extern "C" void kernel_launch(void* const* d_in, const int* in_sizes, int n_in,
                              void* d_out, int out_size, void* d_ws, size_t ws_size,
                              hipStream_t stream) {
    const float* states       = (const float*)d_in[0];
    const int*   p2m          = (const int*)  d_in[1];
    const int*   comp_mask    = (const int*)  d_in[3];
    const float* p_emb        = (const float*)d_in[4];
    const float* d_W          = (const float*)d_in[5];
    const float* d_b          = (const float*)d_in[6];
    const float* lane_W       = (const float*)d_in[7];
    const float* lane_b       = (const float*)d_in[8];
    const float* lane_conv_W  = (const float*)d_in[9];
    const float* lane_conv_b  = (const float*)d_in[10];
    const float* rel_emb      = (const float*)d_in[11];
    const float* rel_conv_W   = (const float*)d_in[12];
    const float* rel_conv_b   = (const float*)d_in[13];
    const float* hid_W        = (const float*)d_in[14];
    const float* hid_b        = (const float*)d_in[15];
    const float* merge_W      = (const float*)d_in[16];
    const float* merge_b      = (const float*)d_in[17];
    float* out = (float*)d_out;
    float* ws  = (float*)d_ws;

    frap_setup<<<64, 256, 0, stream>>>(p2m, comp_mask, p_emb, d_W, d_b, lane_W, lane_b,
        lane_conv_W, lane_conv_b, rel_emb, rel_conv_W, rel_conv_b, hid_W, hid_b,
        merge_W, merge_b, ws);

    int B = in_sizes[0] / 13;
    int grid = (B + 63) / 64;
    frap_main<<<grid, 512, 0, stream>>>(states, ws, out, B);
}

// Round 7
// 55.525 us; speedup vs baseline: 10.1585x; 1.2129x over previous
//
#include <hip/hip_runtime.h>
#include <math.h>

typedef _Float16 h2 __attribute__((ext_vector_type(2)));
typedef unsigned int uint32;

// ---- d_ws layout (float indices) ----
#define WS_HB  0      // hid_b[20]
#define WS_MW  20     // merge_W[20]
#define WS_MB  40     // merge_b (+pad)
#define WS_B0  44     // base[2][16]
#define WS_Z0  76     // zvec[2][16]
#define WS_W4  108    // lane_W[:, :4] as [h][k] : 64
#define WS_DW  172    // d_W[4]
#define WS_DB  176    // d_b[4]
#define WS_WUH 180    // uint32 WuH[20][8]: f16-pair packed Wu = 160
#define WS_WVH 340    // uint32 WvH[20][8] = 160
#define WS_UB  500    // lane_conv_b[20]
#define WS_PM  520    // int pmask[8]
#define WS_HH  528    // uint32 Hh[2][20][10]: f16-packed hid_W⊙R_cf = 400
// total 928 floats

__global__ void frap_setup(
    const int* __restrict__ p2m, const int* __restrict__ comp_mask,
    const float* __restrict__ p_emb, const float* __restrict__ d_W, const float* __restrict__ d_b,
    const float* __restrict__ lane_W, const float* __restrict__ lane_b,
    const float* __restrict__ lane_conv_W, const float* __restrict__ lane_conv_b,
    const float* __restrict__ rel_emb, const float* __restrict__ rel_conv_W, const float* __restrict__ rel_conv_b,
    const float* __restrict__ hid_W, const float* __restrict__ hid_b,
    const float* __restrict__ merge_W, const float* __restrict__ merge_b,
    float* __restrict__ ws)
{
    __shared__ float R[40];     // rel factors R[c][o]
    const int t = threadIdx.x;
    const int NTH = 256;

    if (t < 40) {
        int c = t / 20, o = t % 20;
        float s = rel_conv_b[o];
        #pragma unroll
        for (int k = 0; k < 4; ++k)
            s = fmaf(rel_conv_W[o*4+k], fmaxf(rel_emb[c*4+k], 0.f), s);
        R[t] = fmaxf(s, 0.f);
    }
    __syncthreads();

    // Hh[cf][o2][jj] = pack_f16( hid_W[o2][2jj]*R[cf][2jj], hid_W[o2][2jj+1]*R[cf][2jj+1] )
    uint32* Hh = (uint32*)ws + WS_HH;
    for (int e = t; e < 400; e += NTH) {
        int jj = e % 10;
        int o2 = (e / 10) % 20;
        int cf = e / 200;
        float a = hid_W[o2*20 + 2*jj]     * R[cf*20 + 2*jj];
        float b = hid_W[o2*20 + 2*jj + 1] * R[cf*20 + 2*jj + 1];
        _Float16 ha = (_Float16)a, hb = (_Float16)b;   // RTN
        Hh[e] = (uint32)__builtin_bit_cast(unsigned short, ha)
              | ((uint32)__builtin_bit_cast(unsigned short, hb) << 16);
    }
    // WuH/WvH packed f16 pairs over h
    uint32* WuH = (uint32*)ws + WS_WUH;
    uint32* WvH = (uint32*)ws + WS_WVH;
    for (int e = t; e < 160; e += NTH) {
        int jj = e % 8, o = e / 8;
        _Float16 a0 = (_Float16)lane_conv_W[o*32 + 2*jj];
        _Float16 a1 = (_Float16)lane_conv_W[o*32 + 2*jj + 1];
        _Float16 b0 = (_Float16)lane_conv_W[o*32 + 16 + 2*jj];
        _Float16 b1 = (_Float16)lane_conv_W[o*32 + 16 + 2*jj + 1];
        WuH[e] = (uint32)__builtin_bit_cast(unsigned short, a0)
               | ((uint32)__builtin_bit_cast(unsigned short, a1) << 16);
        WvH[e] = (uint32)__builtin_bit_cast(unsigned short, b0)
               | ((uint32)__builtin_bit_cast(unsigned short, b1) << 16);
    }
    for (int i = t; i < 20; i += NTH) {
        ws[WS_HB + i] = hid_b[i];
        ws[WS_MW + i] = merge_W[i];
        ws[WS_UB + i] = lane_conv_b[i];
    }
    if (t == 0) ws[WS_MB] = merge_b[0];
    for (int i = t; i < 32; i += NTH) {
        int c = i >> 4, h = i & 15;
        float s = lane_b[h];
        #pragma unroll
        for (int k = 0; k < 4; ++k) {
            float sg = 1.f/(1.f + __expf(-p_emb[c*4+k]));
            s = fmaf(lane_W[h*8+4+k], sg, s);
        }
        ws[WS_B0 + c*16 + h] = s;              // base_c[h]
        float z = s;
        #pragma unroll
        for (int k = 0; k < 4; ++k) {
            float sg = 1.f/(1.f + __expf(-d_b[k]));
            z = fmaf(lane_W[h*8+k], sg, z);
        }
        ws[WS_Z0 + c*16 + h] = fmaxf(z, 0.f);  // zvec_c[h]
    }
    for (int i = t; i < 64; i += NTH) ws[WS_W4 + i] = lane_W[(i>>2)*8 + (i&3)];
    if (t < 4) { ws[WS_DW + t] = d_W[t]; ws[WS_DB + t] = d_b[t]; }
    int* wi = (int*)ws;
    for (int i = t; i < 8; i += NTH) {
        int mk = 0;
        for (int m = 0; m < 12; ++m) mk |= (p2m[i*12 + m] & 1) << m;
        wi[WS_PM + i] = mk;
    }
}

__device__ __forceinline__ uint32 pkrtz(float a, float b) {
    return __builtin_bit_cast(uint32, __builtin_amdgcn_cvt_pkrtz(a, b));
}

__global__ __launch_bounds__(512, 8) void frap_main(
    const float* __restrict__ states, const int* __restrict__ comp_mask,
    const float* __restrict__ ws, float* __restrict__ out, int B)
{
    __shared__ uint32 v_h[512*10];                 // packed-f16 v, 20,480 B
    const int tid  = threadIdx.x;
    const int lane = tid & 63;
    const int p    = __builtin_amdgcn_readfirstlane(tid >> 6);  // wave-uniform phase
    const int b    = blockIdx.x * 64 + lane;
    const int bc   = b < B ? b : B - 1;
    const int* wi  = (const int*)ws;

    const float* srow = states + (size_t)bc * 13;
    const int cmask = wi[WS_PM + (int)srow[0]];    // lane-varying
    float dm[12];
    #pragma unroll
    for (int m = 0; m < 12; ++m) dm[m] = srow[1+m];

    const int pmask = wi[WS_PM + p];               // scalar

    // ---- stage 1: agg[16] (f32, unchanged from r6) ----
    const int notp = ~pmask & 0xFFF;
    const float cnt1 = (float)__popc(cmask & notp);
    const float cnt0 = (float)__popc(~cmask & notp);

    float agg[16];
    #pragma unroll
    for (int h = 0; h < 16; ++h)
        agg[h] = fmaf(cnt0, ws[WS_Z0+h], cnt1 * ws[WS_Z0+16+h]);

    #pragma unroll
    for (int m = 0; m < 12; ++m) {
        if ((pmask >> m) & 1) {                    // wave-uniform branch
            const bool cbit = (cmask >> m) & 1;
            float e[4];
            #pragma unroll
            for (int k = 0; k < 4; ++k) {
                float xx = fmaf(dm[m], ws[WS_DW+k], ws[WS_DB+k]);
                e[k] = __builtin_amdgcn_rcpf(1.f + __expf(-xx));
            }
            #pragma unroll
            for (int h = 0; h < 16; ++h) {
                float t = cbit ? ws[WS_B0+16+h] : ws[WS_B0+h];
                #pragma unroll
                for (int k = 0; k < 4; ++k)
                    t = fmaf(ws[WS_W4 + h*4 + k], e[k], t);
                agg[h] += fmaxf(t, 0.f);
            }
        }
    }

    // ---- stage 2: pack agg -> f16; u,v via fdot2; pack results ----
    uint32 aggh[8];
    #pragma unroll
    for (int jj = 0; jj < 8; ++jj) aggh[jj] = pkrtz(agg[2*jj], agg[2*jj+1]);

    const uint32* WuH = (const uint32*)ws + WS_WUH;
    const uint32* WvH = (const uint32*)ws + WS_WVH;
    uint32 upk[10], vpk[10];
    #pragma unroll
    for (int op = 0; op < 10; ++op) {
        float su0 = ws[WS_UB + 2*op], su1 = ws[WS_UB + 2*op + 1];
        float sv0 = 0.f, sv1 = 0.f;
        #pragma unroll
        for (int jj = 0; jj < 8; ++jj) {
            h2 a = __builtin_bit_cast(h2, aggh[jj]);
            su0 = __builtin_amdgcn_fdot2(__builtin_bit_cast(h2, WuH[(2*op)*8 + jj]),   a, su0, false);
            su1 = __builtin_amdgcn_fdot2(__builtin_bit_cast(h2, WuH[(2*op+1)*8 + jj]), a, su1, false);
            sv0 = __builtin_amdgcn_fdot2(__builtin_bit_cast(h2, WvH[(2*op)*8 + jj]),   a, sv0, false);
            sv1 = __builtin_amdgcn_fdot2(__builtin_bit_cast(h2, WvH[(2*op+1)*8 + jj]), a, sv1, false);
        }
        upk[op] = pkrtz(su0, su1);
        vpk[op] = pkrtz(sv0, sv1);
    }
    {
        uint32* vdst = &v_h[tid*10];
        #pragma unroll
        for (int jj = 0; jj < 10; ++jj) vdst[jj] = vpk[jj];
    }
    __syncthreads();

    // ---- stage 3: y = pkmax(u+v_j, 0); s = Hh[cf]·y via fdot2 ----
    float q_acc = 7.f * ws[WS_MB];
    const uint32* HhB = (const uint32*)ws + WS_HH;
    const h2 z2 = {(_Float16)0.f, (_Float16)0.f};
    for (int qi = 0; qi < 7; ++qi) {
        const int j  = qi + (qi >= p ? 1 : 0);              // scalar
        const int cf = comp_mask[p*7 + qi];                 // scalar, qi-varying
        const uint32* Hq = HhB + cf*200;                    // K$-resident (1.6 KB total)
        const uint32* vj = &v_h[(j*64 + lane)*10];
        uint32 ypk[10];
        #pragma unroll
        for (int jj = 0; jj < 10; ++jj) {
            h2 t = __builtin_bit_cast(h2, upk[jj]) + __builtin_bit_cast(h2, vj[jj]);
            ypk[jj] = __builtin_bit_cast(uint32, __builtin_elementwise_max(t, z2));
        }
        #pragma unroll
        for (int o2 = 0; o2 < 20; ++o2) {
            float s = ws[WS_HB + o2];
            #pragma unroll
            for (int jj = 0; jj < 10; ++jj)
                s = __builtin_amdgcn_fdot2(__builtin_bit_cast(h2, Hq[o2*10 + jj]),
                                           __builtin_bit_cast(h2, ypk[jj]), s, false);
            q_acc = fmaf(ws[WS_MW + o2], fmaxf(s, 0.f), q_acc);
        }
    }
    if (b < B) out[(size_t)b*8 + p] = q_acc;
}

extern "C" void kernel_launch(void* const* d_in, const int* in_sizes, int n_in,
                              void* d_out, int out_size, void* d_ws, size_t ws_size,
                              hipStream_t stream) {
    const float* states       = (const float*)d_in[0];
    const int*   p2m          = (const int*)  d_in[1];
    const int*   comp_mask    = (const int*)  d_in[3];
    const float* p_emb        = (const float*)d_in[4];
    const float* d_W          = (const float*)d_in[5];
    const float* d_b          = (const float*)d_in[6];
    const float* lane_W       = (const float*)d_in[7];
    const float* lane_b       = (const float*)d_in[8];
    const float* lane_conv_W  = (const float*)d_in[9];
    const float* lane_conv_b  = (const float*)d_in[10];
    const float* rel_emb      = (const float*)d_in[11];
    const float* rel_conv_W   = (const float*)d_in[12];
    const float* rel_conv_b   = (const float*)d_in[13];
    const float* hid_W        = (const float*)d_in[14];
    const float* hid_b        = (const float*)d_in[15];
    const float* merge_W      = (const float*)d_in[16];
    const float* merge_b      = (const float*)d_in[17];
    float* out = (float*)d_out;
    float* ws  = (float*)d_ws;

    frap_setup<<<1, 256, 0, stream>>>(p2m, comp_mask, p_emb, d_W, d_b, lane_W, lane_b,
        lane_conv_W, lane_conv_b, rel_emb, rel_conv_W, rel_conv_b, hid_W, hid_b,
        merge_W, merge_b, ws);

    int B = in_sizes[0] / 13;
    int grid = (B + 63) / 64;
    frap_main<<<grid, 512, 0, stream>>>(states, comp_mask, ws, out, B);
}

// Round 8
// 40.600 us; speedup vs baseline: 13.8929x; 1.3676x over previous
//
#include <hip/hip_runtime.h>
#include <math.h>

typedef _Float16 h2 __attribute__((ext_vector_type(2)));
typedef _Float16 half8 __attribute__((ext_vector_type(8)));
typedef float f32x16 __attribute__((ext_vector_type(16)));
typedef unsigned int uint32;
typedef unsigned int uint32x4 __attribute__((ext_vector_type(4)));

// ---- d_ws layout (float indices) ----
#define WS_MB  0      // merge_b (+pad)
#define WS_B0  4      // base[2][16]
#define WS_Z0  36     // zvec[2][16]
#define WS_W4  68     // lane_W[:, :4] as [h][k] : 64
#define WS_DW  132    // d_W[4]
#define WS_DB  136    // d_b[4]
#define WS_WUH 140    // uint32 WuH[20][8]: f16-pair packed Wu = 160
#define WS_WVH 300    // uint32 WvH[20][8] = 160
#define WS_UB  460    // lane_conv_b[20]
#define WS_PM  480    // int pmask[8]
#define WS_HBP 488    // float[2][16]: hid_b permuted to C-layout rows (0 if row>=20)
#define WS_MWP 520    // float[2][16]: merge_W permuted to C-layout rows (0 if row>=20)
#define WS_HA  552    // uint32[2cf][2step][64][4]: A-fragments of H_cf (f16 pairs) = 1024
// total 1576 floats

__global__ void frap_setup(
    const int* __restrict__ p2m, const int* __restrict__ comp_mask,
    const float* __restrict__ p_emb, const float* __restrict__ d_W, const float* __restrict__ d_b,
    const float* __restrict__ lane_W, const float* __restrict__ lane_b,
    const float* __restrict__ lane_conv_W, const float* __restrict__ lane_conv_b,
    const float* __restrict__ rel_emb, const float* __restrict__ rel_conv_W, const float* __restrict__ rel_conv_b,
    const float* __restrict__ hid_W, const float* __restrict__ hid_b,
    const float* __restrict__ merge_W, const float* __restrict__ merge_b,
    float* __restrict__ ws)
{
    __shared__ float R[40];     // rel factors R[c][o]
    const int t = threadIdx.x;
    const int NTH = 256;

    if (t < 40) {
        int c = t / 20, o = t % 20;
        float s = rel_conv_b[o];
        #pragma unroll
        for (int k = 0; k < 4; ++k)
            s = fmaf(rel_conv_W[o*4+k], fmaxf(rel_emb[c*4+k], 0.f), s);
        R[t] = fmaxf(s, 0.f);
    }
    __syncthreads();

    // A-fragments for v_mfma_f32_32x32x16_f16:
    // A row = lane&31 (= o2), k = (lane>>5)*8 + v, dword j holds (k=2j, k=2j+1).
    // HA[cf][step][lane][j]; step selects k-base 0/16. Zero-padded for row>=20, k>=20.
    uint32* HA = (uint32*)ws + WS_HA;
    for (int e = t; e < 1024; e += NTH) {
        int j    = e & 3;
        int lane = (e >> 2) & 63;
        int step = (e >> 8) & 1;
        int cf   = e >> 9;
        int row  = lane & 31;
        int k0   = step*16 + (lane >> 5)*8 + 2*j;
        float a = 0.f, bq = 0.f;
        if (row < 20) {
            if (k0     < 20) a  = hid_W[row*20 + k0]     * R[cf*20 + k0];
            if (k0 + 1 < 20) bq = hid_W[row*20 + k0 + 1] * R[cf*20 + k0 + 1];
        }
        _Float16 ha_ = (_Float16)a, hb_ = (_Float16)bq;   // RTN
        HA[e] = (uint32)__builtin_bit_cast(unsigned short, ha_)
              | ((uint32)__builtin_bit_cast(unsigned short, hb_) << 16);
    }
    // hid_b / merge_W permuted into C-fragment row order: row=(reg&3)+8*(reg>>2)+4*half
    for (int e = t; e < 32; e += NTH) {
        int half = e >> 4, r = e & 15;
        int row = (r & 3) + 8*(r >> 2) + 4*half;
        ws[WS_HBP + e] = row < 20 ? hid_b[row]   : 0.f;
        ws[WS_MWP + e] = row < 20 ? merge_W[row] : 0.f;
    }
    // WuH/WvH packed f16 pairs over h
    uint32* WuH = (uint32*)ws + WS_WUH;
    uint32* WvH = (uint32*)ws + WS_WVH;
    for (int e = t; e < 160; e += NTH) {
        int jj = e % 8, o = e / 8;
        _Float16 a0 = (_Float16)lane_conv_W[o*32 + 2*jj];
        _Float16 a1 = (_Float16)lane_conv_W[o*32 + 2*jj + 1];
        _Float16 b0 = (_Float16)lane_conv_W[o*32 + 16 + 2*jj];
        _Float16 b1 = (_Float16)lane_conv_W[o*32 + 16 + 2*jj + 1];
        WuH[e] = (uint32)__builtin_bit_cast(unsigned short, a0)
               | ((uint32)__builtin_bit_cast(unsigned short, a1) << 16);
        WvH[e] = (uint32)__builtin_bit_cast(unsigned short, b0)
               | ((uint32)__builtin_bit_cast(unsigned short, b1) << 16);
    }
    for (int i = t; i < 20; i += NTH) ws[WS_UB + i] = lane_conv_b[i];
    if (t == 0) ws[WS_MB] = merge_b[0];
    for (int i = t; i < 32; i += NTH) {
        int c = i >> 4, h = i & 15;
        float s = lane_b[h];
        #pragma unroll
        for (int k = 0; k < 4; ++k) {
            float sg = 1.f/(1.f + __expf(-p_emb[c*4+k]));
            s = fmaf(lane_W[h*8+4+k], sg, s);
        }
        ws[WS_B0 + c*16 + h] = s;              // base_c[h]
        float z = s;
        #pragma unroll
        for (int k = 0; k < 4; ++k) {
            float sg = 1.f/(1.f + __expf(-d_b[k]));
            z = fmaf(lane_W[h*8+k], sg, z);
        }
        ws[WS_Z0 + c*16 + h] = fmaxf(z, 0.f);  // zvec_c[h]
    }
    for (int i = t; i < 64; i += NTH) ws[WS_W4 + i] = lane_W[(i>>2)*8 + (i&3)];
    if (t < 4) { ws[WS_DW + t] = d_W[t]; ws[WS_DB + t] = d_b[t]; }
    int* wi = (int*)ws;
    for (int i = t; i < 8; i += NTH) {
        int mk = 0;
        for (int m = 0; m < 12; ++m) mk |= (p2m[i*12 + m] & 1) << m;
        wi[WS_PM + i] = mk;
    }
}

__device__ __forceinline__ uint32 pkrtz(float a, float b) {
    return __builtin_bit_cast(uint32, __builtin_amdgcn_cvt_pkrtz(a, b));
}

__global__ __launch_bounds__(512, 4) void frap_main(
    const float* __restrict__ states, const int* __restrict__ comp_mask,
    const float* __restrict__ ws, float* __restrict__ out, int B)
{
    __shared__ uint32 v_h[512*10];                 // packed-f16 v, 20,480 B
    const int tid  = threadIdx.x;
    const int lane = tid & 63;
    const int p    = __builtin_amdgcn_readfirstlane(tid >> 6);  // wave-uniform phase
    const int b    = blockIdx.x * 64 + lane;
    const int bc   = b < B ? b : B - 1;
    const int* wi  = (const int*)ws;

    const float* srow = states + (size_t)bc * 13;
    const int cmask = wi[WS_PM + (int)srow[0]];    // lane-varying
    float dm[12];
    #pragma unroll
    for (int m = 0; m < 12; ++m) dm[m] = srow[1+m];

    const int pmask = wi[WS_PM + p];               // scalar

    // ---- stage 1: agg[16] (f32, unchanged from r7) ----
    const int notp = ~pmask & 0xFFF;
    const float cnt1 = (float)__popc(cmask & notp);
    const float cnt0 = (float)__popc(~cmask & notp);

    float agg[16];
    #pragma unroll
    for (int h = 0; h < 16; ++h)
        agg[h] = fmaf(cnt0, ws[WS_Z0+h], cnt1 * ws[WS_Z0+16+h]);

    #pragma unroll
    for (int m = 0; m < 12; ++m) {
        if ((pmask >> m) & 1) {                    // wave-uniform branch
            const bool cbit = (cmask >> m) & 1;
            float e[4];
            #pragma unroll
            for (int k = 0; k < 4; ++k) {
                float xx = fmaf(dm[m], ws[WS_DW+k], ws[WS_DB+k]);
                e[k] = __builtin_amdgcn_rcpf(1.f + __expf(-xx));
            }
            #pragma unroll
            for (int h = 0; h < 16; ++h) {
                float t = cbit ? ws[WS_B0+16+h] : ws[WS_B0+h];
                #pragma unroll
                for (int k = 0; k < 4; ++k)
                    t = fmaf(ws[WS_W4 + h*4 + k], e[k], t);
                agg[h] += fmaxf(t, 0.f);
            }
        }
    }

    // ---- stage 2: pack agg -> f16; u,v via fdot2; pack results (unchanged from r7) ----
    uint32 aggh[8];
    #pragma unroll
    for (int jj = 0; jj < 8; ++jj) aggh[jj] = pkrtz(agg[2*jj], agg[2*jj+1]);

    const uint32* WuH = (const uint32*)ws + WS_WUH;
    const uint32* WvH = (const uint32*)ws + WS_WVH;
    uint32 upk[10], vpk[10];
    #pragma unroll
    for (int op = 0; op < 10; ++op) {
        float su0 = ws[WS_UB + 2*op], su1 = ws[WS_UB + 2*op + 1];
        float sv0 = 0.f, sv1 = 0.f;
        #pragma unroll
        for (int jj = 0; jj < 8; ++jj) {
            h2 a = __builtin_bit_cast(h2, aggh[jj]);
            su0 = __builtin_amdgcn_fdot2(__builtin_bit_cast(h2, WuH[(2*op)*8 + jj]),   a, su0, false);
            su1 = __builtin_amdgcn_fdot2(__builtin_bit_cast(h2, WuH[(2*op+1)*8 + jj]), a, su1, false);
            sv0 = __builtin_amdgcn_fdot2(__builtin_bit_cast(h2, WvH[(2*op)*8 + jj]),   a, sv0, false);
            sv1 = __builtin_amdgcn_fdot2(__builtin_bit_cast(h2, WvH[(2*op+1)*8 + jj]), a, sv1, false);
        }
        upk[op] = pkrtz(su0, su1);
        vpk[op] = pkrtz(sv0, sv1);
    }
    {
        uint32* vdst = &v_h[tid*10];
        #pragma unroll
        for (int jj = 0; jj < 10; ++jj) vdst[jj] = vpk[jj];
    }
    __syncthreads();

    // ---- stage 3: MFMA. Per qi: s[o2][sample] = H_cf · y + hid_b; q += mw·relu(s) ----
    // Preload both cf A-fragment variants (2 K-steps each) + permuted hid_b/merge_W.
    const uint32* HAp = (const uint32*)ws + WS_HA;
    half8 A00, A10, A01, A11;  // A{step}{cf}
    {
        uint32x4 w0 = *(const uint32x4*)(HAp + (0*64 + lane)*4);
        uint32x4 w1 = *(const uint32x4*)(HAp + (1*64 + lane)*4);
        uint32x4 w2 = *(const uint32x4*)(HAp + (2*64 + lane)*4);
        uint32x4 w3 = *(const uint32x4*)(HAp + (3*64 + lane)*4);
        A00 = __builtin_bit_cast(half8, w0);
        A10 = __builtin_bit_cast(half8, w1);
        A01 = __builtin_bit_cast(half8, w2);
        A11 = __builtin_bit_cast(half8, w3);
    }
    const int halfsel = lane >> 5;
    f32x16 hbacc;
    #pragma unroll
    for (int r = 0; r < 16; ++r) hbacc[r] = ws[WS_HBP + halfsel*16 + r];
    float mwv[12];
    #pragma unroll
    for (int r = 0; r < 12; ++r) mwv[r] = ws[WS_MWP + halfsel*16 + r];

    const int srcT0 = (lane & 31) * 4;         // partner holding sample lane&31
    const int srcT1 = (32 | (lane & 31)) * 4;  // partner holding sample 32|(lane&31)
    const int srcX  = (lane ^ 32) * 4;
    const bool lo = lane < 32;
    const h2 z2 = {(_Float16)0.f, (_Float16)0.f};

    float qA = 0.f, qB = 0.f;
    for (int qi = 0; qi < 7; ++qi) {
        const int j   = qi + (qi >= p ? 1 : 0);            // scalar
        const bool cf = comp_mask[p*7 + qi] != 0;          // scalar
        const uint32* vj = &v_h[(j*64 + lane)*10];
        uint32 ypk[10];
        #pragma unroll
        for (int jj = 0; jj < 10; ++jj) {
            h2 t = __builtin_bit_cast(h2, upk[jj]) + __builtin_bit_cast(h2, vj[jj]);
            ypk[jj] = __builtin_bit_cast(uint32, __builtin_elementwise_max(t, z2));
        }
        // B-fragments: col=lane&31 (sample in tile), k=(lane>>5)*8+v.
        uint32 f00[4], f10[4];
        #pragma unroll
        for (int j2 = 0; j2 < 4; ++j2) {
            uint32 t0 = (uint32)__builtin_amdgcn_ds_bpermute(srcT0, (int)ypk[4+j2]);
            uint32 t1 = (uint32)__builtin_amdgcn_ds_bpermute(srcT1, (int)ypk[j2]);
            f00[j2] = lo ? ypk[j2] : t0;       // tile0 K-step0
            f10[j2] = lo ? t1 : ypk[4+j2];     // tile1 K-step0
        }
        uint32 t8 = (uint32)__builtin_amdgcn_ds_bpermute(srcT1, (int)ypk[8]);
        uint32 t9 = (uint32)__builtin_amdgcn_ds_bpermute(srcT1, (int)ypk[9]);
        uint32x4 f00v = {f00[0], f00[1], f00[2], f00[3]};
        uint32x4 f10v = {f10[0], f10[1], f10[2], f10[3]};
        uint32x4 f01v = {lo ? ypk[8] : 0u, lo ? ypk[9] : 0u, 0u, 0u};  // tile0 K-step1
        uint32x4 f11v = {lo ? t8 : 0u,     lo ? t9 : 0u,     0u, 0u};  // tile1 K-step1

        half8 A0 = cf ? A01 : A00;
        half8 A1 = cf ? A11 : A10;

        f32x16 c0 = __builtin_amdgcn_mfma_f32_32x32x16_f16(A0, __builtin_bit_cast(half8, f00v), hbacc, 0, 0, 0);
        c0 = __builtin_amdgcn_mfma_f32_32x32x16_f16(A1, __builtin_bit_cast(half8, f01v), c0, 0, 0, 0);
        f32x16 c1 = __builtin_amdgcn_mfma_f32_32x32x16_f16(A0, __builtin_bit_cast(half8, f10v), hbacc, 0, 0, 0);
        c1 = __builtin_amdgcn_mfma_f32_32x32x16_f16(A1, __builtin_bit_cast(half8, f11v), c1, 0, 0, 0);

        // regs 12..15 are rows >=20 for both halves (mw=0) -> skip uniformly
        #pragma unroll
        for (int r = 0; r < 12; ++r) qA = fmaf(mwv[r], fmaxf(c0[r], 0.f), qA);
        #pragma unroll
        for (int r = 0; r < 12; ++r) qB = fmaf(mwv[r], fmaxf(c1[r], 0.f), qB);
    }

    // combine lane halves: sample s<32 rows split across lanes (s, s+32) in tile0; s>=32 in tile1
    float sA = __builtin_bit_cast(float, __builtin_amdgcn_ds_bpermute(srcX, __builtin_bit_cast(int, qA)));
    float sB = __builtin_bit_cast(float, __builtin_amdgcn_ds_bpermute(srcX, __builtin_bit_cast(int, qB)));
    float qv = (lo ? qA + sA : qB + sB) + 7.f * ws[WS_MB];
    if (b < B) out[(size_t)b*8 + p] = qv;
}

extern "C" void kernel_launch(void* const* d_in, const int* in_sizes, int n_in,
                              void* d_out, int out_size, void* d_ws, size_t ws_size,
                              hipStream_t stream) {
    const float* states       = (const float*)d_in[0];
    const int*   p2m          = (const int*)  d_in[1];
    const int*   comp_mask    = (const int*)  d_in[3];
    const float* p_emb        = (const float*)d_in[4];
    const float* d_W          = (const float*)d_in[5];
    const float* d_b          = (const float*)d_in[6];
    const float* lane_W       = (const float*)d_in[7];
    const float* lane_b       = (const float*)d_in[8];
    const float* lane_conv_W  = (const float*)d_in[9];
    const float* lane_conv_b  = (const float*)d_in[10];
    const float* rel_emb      = (const float*)d_in[11];
    const float* rel_conv_W   = (const float*)d_in[12];
    const float* rel_conv_b   = (const float*)d_in[13];
    const float* hid_W        = (const float*)d_in[14];
    const float* hid_b        = (const float*)d_in[15];
    const float* merge_W      = (const float*)d_in[16];
    const float* merge_b      = (const float*)d_in[17];
    float* out = (float*)d_out;
    float* ws  = (float*)d_ws;

    frap_setup<<<1, 256, 0, stream>>>(p2m, comp_mask, p_emb, d_W, d_b, lane_W, lane_b,
        lane_conv_W, lane_conv_b, rel_emb, rel_conv_W, rel_conv_b, hid_W, hid_b,
        merge_W, merge_b, ws);

    int B = in_sizes[0] / 13;
    int grid = (B + 63) / 64;
    frap_main<<<grid, 512, 0, stream>>>(states, comp_mask, ws, out, B);
}

// Round 9
// 37.157 us; speedup vs baseline: 15.1804x; 1.0927x over previous
//
#include <hip/hip_runtime.h>
#include <math.h>

typedef _Float16 h2 __attribute__((ext_vector_type(2)));
typedef _Float16 half8 __attribute__((ext_vector_type(8)));
typedef float f32x16 __attribute__((ext_vector_type(16)));
typedef unsigned int uint32;
typedef unsigned int uint32x4 __attribute__((ext_vector_type(4)));
typedef unsigned int uint32x2 __attribute__((ext_vector_type(2)));

// ---- d_ws layout (float indices) ----
#define WS_MB  0      // merge_b (+pad)
#define WS_B0  4      // base[2][16]
#define WS_Z0  36     // zvec[2][16]
#define WS_W4  68     // lane_W[:, :4] as [h][k] : 64
#define WS_DW  132    // d_W[4]
#define WS_DB  136    // d_b[4]
#define WS_WUH 140    // uint32 WuH[20][8]: f16-pair packed Wu = 160
#define WS_WVH 300    // uint32 WvH[20][8] = 160
#define WS_UB  460    // lane_conv_b[20]
#define WS_PM  480    // int pmask[8]
#define WS_HBP 488    // float[2][16]: hid_b permuted to C-layout rows (0 if row>=20)
#define WS_MWP 520    // float[2][16]: merge_W permuted to C-layout rows (0 if row>=20)
#define WS_HA  552    // uint32[2cf][2step][64][4]: A-fragments of H_cf (f16 pairs) = 1024
// total 1576 floats

__global__ void frap_setup(
    const int* __restrict__ p2m, const int* __restrict__ comp_mask,
    const float* __restrict__ p_emb, const float* __restrict__ d_W, const float* __restrict__ d_b,
    const float* __restrict__ lane_W, const float* __restrict__ lane_b,
    const float* __restrict__ lane_conv_W, const float* __restrict__ lane_conv_b,
    const float* __restrict__ rel_emb, const float* __restrict__ rel_conv_W, const float* __restrict__ rel_conv_b,
    const float* __restrict__ hid_W, const float* __restrict__ hid_b,
    const float* __restrict__ merge_W, const float* __restrict__ merge_b,
    float* __restrict__ ws)
{
    __shared__ float R[40];     // rel factors R[c][o]
    const int t = threadIdx.x;
    const int NTH = 256;

    if (t < 40) {
        int c = t / 20, o = t % 20;
        float s = rel_conv_b[o];
        #pragma unroll
        for (int k = 0; k < 4; ++k)
            s = fmaf(rel_conv_W[o*4+k], fmaxf(rel_emb[c*4+k], 0.f), s);
        R[t] = fmaxf(s, 0.f);
    }
    __syncthreads();

    // A-fragments for v_mfma_f32_32x32x16_f16:
    // A row = lane&31 (= o2), k = (lane>>5)*8 + v, dword j holds (k=2j, k=2j+1).
    uint32* HA = (uint32*)ws + WS_HA;
    for (int e = t; e < 1024; e += NTH) {
        int j    = e & 3;
        int lane = (e >> 2) & 63;
        int step = (e >> 8) & 1;
        int cf   = e >> 9;
        int row  = lane & 31;
        int k0   = step*16 + (lane >> 5)*8 + 2*j;
        float a = 0.f, bq = 0.f;
        if (row < 20) {
            if (k0     < 20) a  = hid_W[row*20 + k0]     * R[cf*20 + k0];
            if (k0 + 1 < 20) bq = hid_W[row*20 + k0 + 1] * R[cf*20 + k0 + 1];
        }
        _Float16 ha_ = (_Float16)a, hb_ = (_Float16)bq;   // RTN
        HA[e] = (uint32)__builtin_bit_cast(unsigned short, ha_)
              | ((uint32)__builtin_bit_cast(unsigned short, hb_) << 16);
    }
    // hid_b / merge_W permuted into C-fragment row order: row=(reg&3)+8*(reg>>2)+4*half
    for (int e = t; e < 32; e += NTH) {
        int half = e >> 4, r = e & 15;
        int row = (r & 3) + 8*(r >> 2) + 4*half;
        ws[WS_HBP + e] = row < 20 ? hid_b[row]   : 0.f;
        ws[WS_MWP + e] = row < 20 ? merge_W[row] : 0.f;
    }
    // WuH/WvH packed f16 pairs over h
    uint32* WuH = (uint32*)ws + WS_WUH;
    uint32* WvH = (uint32*)ws + WS_WVH;
    for (int e = t; e < 160; e += NTH) {
        int jj = e % 8, o = e / 8;
        _Float16 a0 = (_Float16)lane_conv_W[o*32 + 2*jj];
        _Float16 a1 = (_Float16)lane_conv_W[o*32 + 2*jj + 1];
        _Float16 b0 = (_Float16)lane_conv_W[o*32 + 16 + 2*jj];
        _Float16 b1 = (_Float16)lane_conv_W[o*32 + 16 + 2*jj + 1];
        WuH[e] = (uint32)__builtin_bit_cast(unsigned short, a0)
               | ((uint32)__builtin_bit_cast(unsigned short, a1) << 16);
        WvH[e] = (uint32)__builtin_bit_cast(unsigned short, b0)
               | ((uint32)__builtin_bit_cast(unsigned short, b1) << 16);
    }
    for (int i = t; i < 20; i += NTH) ws[WS_UB + i] = lane_conv_b[i];
    if (t == 0) ws[WS_MB] = merge_b[0];
    for (int i = t; i < 32; i += NTH) {
        int c = i >> 4, h = i & 15;
        float s = lane_b[h];
        #pragma unroll
        for (int k = 0; k < 4; ++k) {
            float sg = 1.f/(1.f + __expf(-p_emb[c*4+k]));
            s = fmaf(lane_W[h*8+4+k], sg, s);
        }
        ws[WS_B0 + c*16 + h] = s;              // base_c[h]
        float z = s;
        #pragma unroll
        for (int k = 0; k < 4; ++k) {
            float sg = 1.f/(1.f + __expf(-d_b[k]));
            z = fmaf(lane_W[h*8+k], sg, z);
        }
        ws[WS_Z0 + c*16 + h] = fmaxf(z, 0.f);  // zvec_c[h]
    }
    for (int i = t; i < 64; i += NTH) ws[WS_W4 + i] = lane_W[(i>>2)*8 + (i&3)];
    if (t < 4) { ws[WS_DW + t] = d_W[t]; ws[WS_DB + t] = d_b[t]; }
    int* wi = (int*)ws;
    for (int i = t; i < 8; i += NTH) {
        int mk = 0;
        for (int m = 0; m < 12; ++m) mk |= (p2m[i*12 + m] & 1) << m;
        wi[WS_PM + i] = mk;
    }
}

__device__ __forceinline__ uint32 pkrtz(float a, float b) {
    return __builtin_bit_cast(uint32, __builtin_amdgcn_cvt_pkrtz(a, b));
}

__global__ __launch_bounds__(512, 4) void frap_main(
    const float* __restrict__ states, const int* __restrict__ comp_mask,
    const float* __restrict__ ws, float* __restrict__ out, int B)
{
    // Union LDS: stage-1 shares t[sample][m][16] f32 (stride 20, 61,440 B);
    // after sync it is reused for packed-f16 v (stride 12, 24,576 B).
    __shared__ float smem_f[12*64*20];
    uint32* v_sm = (uint32*)smem_f;

    const int tid  = threadIdx.x;
    const int lane = tid & 63;
    const int p    = __builtin_amdgcn_readfirstlane(tid >> 6);  // wave-uniform phase
    const int b    = blockIdx.x * 64 + lane;
    const int bc   = b < B ? b : B - 1;
    const int* wi  = (const int*)ws;

    const float* srow = states + (size_t)bc * 13;
    const int cmask = wi[WS_PM + (int)srow[0]];    // lane-varying (per-sample)
    float dm[12];
    #pragma unroll
    for (int m = 0; m < 12; ++m) dm[m] = srow[1+m];

    const int pmask = wi[WS_PM + p];               // scalar

    // ---- stage 1a: thread p computes t[sample][m] for m in {p, p+8 (p<4)} ----
    // t depends only on (sample, m): e = sigmoid(dem[m]*dW+dB) is p-independent.
    // f32, same instruction sequence as r8 -> bit-identical t values.
    auto compute_store_t = [&](int m) {
        const bool cbit = (cmask >> m) & 1;
        float e[4];
        #pragma unroll
        for (int k = 0; k < 4; ++k) {
            float xx = fmaf(dm[m], ws[WS_DW+k], ws[WS_DB+k]);
            e[k] = __builtin_amdgcn_rcpf(1.f + __expf(-xx));
        }
        float* dst = &smem_f[(m*64 + lane)*20];
        #pragma unroll
        for (int h4 = 0; h4 < 16; h4 += 4) {
            float4 t4;
            #pragma unroll
            for (int hh = 0; hh < 4; ++hh) {
                int h = h4 + hh;
                float t = cbit ? ws[WS_B0+16+h] : ws[WS_B0+h];
                #pragma unroll
                for (int k = 0; k < 4; ++k)
                    t = fmaf(ws[WS_W4 + h*4 + k], e[k], t);
                (&t4.x)[hh] = fmaxf(t, 0.f);
            }
            *(float4*)(dst + h4) = t4;
        }
    };
    compute_store_t(p);
    if (p < 4) compute_store_t(p + 8);
    __syncthreads();

    // ---- stage 1b: agg = zvec-fold + sum of my pmask movements' t ----
    const int notp = ~pmask & 0xFFF;
    const float cnt1 = (float)__popc(cmask & notp);
    const float cnt0 = (float)__popc(~cmask & notp);

    float agg[16];
    #pragma unroll
    for (int h = 0; h < 16; ++h)
        agg[h] = fmaf(cnt0, ws[WS_Z0+h], cnt1 * ws[WS_Z0+16+h]);

    #pragma unroll
    for (int m = 0; m < 12; ++m) {
        if ((pmask >> m) & 1) {                    // wave-uniform branch
            const float* src = &smem_f[(m*64 + lane)*20];
            #pragma unroll
            for (int h4 = 0; h4 < 16; h4 += 4) {
                float4 t4 = *(const float4*)(src + h4);
                agg[h4]   += t4.x;
                agg[h4+1] += t4.y;
                agg[h4+2] += t4.z;
                agg[h4+3] += t4.w;
            }
        }
    }

    // ---- stage 2: pack agg -> f16; u,v via fdot2 (unchanged numerics) ----
    uint32 aggh[8];
    #pragma unroll
    for (int jj = 0; jj < 8; ++jj) aggh[jj] = pkrtz(agg[2*jj], agg[2*jj+1]);

    const uint32* WuH = (const uint32*)ws + WS_WUH;
    const uint32* WvH = (const uint32*)ws + WS_WVH;
    uint32 upk[10], vpk[10];
    #pragma unroll
    for (int op = 0; op < 10; ++op) {
        float su0 = ws[WS_UB + 2*op], su1 = ws[WS_UB + 2*op + 1];
        float sv0 = 0.f, sv1 = 0.f;
        #pragma unroll
        for (int jj = 0; jj < 8; ++jj) {
            h2 a = __builtin_bit_cast(h2, aggh[jj]);
            su0 = __builtin_amdgcn_fdot2(__builtin_bit_cast(h2, WuH[(2*op)*8 + jj]),   a, su0, false);
            su1 = __builtin_amdgcn_fdot2(__builtin_bit_cast(h2, WuH[(2*op+1)*8 + jj]), a, su1, false);
            sv0 = __builtin_amdgcn_fdot2(__builtin_bit_cast(h2, WvH[(2*op)*8 + jj]),   a, sv0, false);
            sv1 = __builtin_amdgcn_fdot2(__builtin_bit_cast(h2, WvH[(2*op+1)*8 + jj]), a, sv1, false);
        }
        upk[op] = pkrtz(su0, su1);
        vpk[op] = pkrtz(sv0, sv1);
    }
    __syncthreads();   // all t reads done; safe to overwrite LDS with v

    {
        uint32* vdst = &v_sm[(p*64 + lane)*12];
        uint32x4 w0 = {vpk[0], vpk[1], vpk[2], vpk[3]};
        uint32x4 w1 = {vpk[4], vpk[5], vpk[6], vpk[7]};
        uint32x2 w2 = {vpk[8], vpk[9]};
        *(uint32x4*)(vdst)     = w0;
        *(uint32x4*)(vdst + 4) = w1;
        *(uint32x2*)(vdst + 8) = w2;
    }
    __syncthreads();

    // ---- stage 3: MFMA per qi (unchanged from r8 except vectorized vj loads) ----
    const uint32* HAp = (const uint32*)ws + WS_HA;
    half8 A00, A10, A01, A11;  // A{step}{cf}
    {
        uint32x4 w0 = *(const uint32x4*)(HAp + (0*64 + lane)*4);
        uint32x4 w1 = *(const uint32x4*)(HAp + (1*64 + lane)*4);
        uint32x4 w2 = *(const uint32x4*)(HAp + (2*64 + lane)*4);
        uint32x4 w3 = *(const uint32x4*)(HAp + (3*64 + lane)*4);
        A00 = __builtin_bit_cast(half8, w0);
        A10 = __builtin_bit_cast(half8, w1);
        A01 = __builtin_bit_cast(half8, w2);
        A11 = __builtin_bit_cast(half8, w3);
    }
    const int halfsel = lane >> 5;
    f32x16 hbacc;
    #pragma unroll
    for (int r = 0; r < 16; ++r) hbacc[r] = ws[WS_HBP + halfsel*16 + r];
    float mwv[12];
    #pragma unroll
    for (int r = 0; r < 12; ++r) mwv[r] = ws[WS_MWP + halfsel*16 + r];

    const int srcT0 = (lane & 31) * 4;         // partner holding sample lane&31
    const int srcT1 = (32 | (lane & 31)) * 4;  // partner holding sample 32|(lane&31)
    const int srcX  = (lane ^ 32) * 4;
    const bool lo = lane < 32;
    const h2 z2 = {(_Float16)0.f, (_Float16)0.f};

    float qA = 0.f, qB = 0.f;
    for (int qi = 0; qi < 7; ++qi) {
        const int j   = qi + (qi >= p ? 1 : 0);            // scalar
        const bool cf = comp_mask[p*7 + qi] != 0;          // scalar
        const uint32* vj = &v_sm[(j*64 + lane)*12];
        uint32x4 va = *(const uint32x4*)vj;
        uint32x4 vb = *(const uint32x4*)(vj + 4);
        uint32x2 vc = *(const uint32x2*)(vj + 8);
        uint32 vjw[10] = {va[0], va[1], va[2], va[3], vb[0], vb[1], vb[2], vb[3], vc[0], vc[1]};
        uint32 ypk[10];
        #pragma unroll
        for (int jj = 0; jj < 10; ++jj) {
            h2 t = __builtin_bit_cast(h2, upk[jj]) + __builtin_bit_cast(h2, vjw[jj]);
            ypk[jj] = __builtin_bit_cast(uint32, __builtin_elementwise_max(t, z2));
        }
        // B-fragments: col=lane&31 (sample in tile), k=(lane>>5)*8+v.
        uint32 f00[4], f10[4];
        #pragma unroll
        for (int j2 = 0; j2 < 4; ++j2) {
            uint32 t0 = (uint32)__builtin_amdgcn_ds_bpermute(srcT0, (int)ypk[4+j2]);
            uint32 t1 = (uint32)__builtin_amdgcn_ds_bpermute(srcT1, (int)ypk[j2]);
            f00[j2] = lo ? ypk[j2] : t0;       // tile0 K-step0
            f10[j2] = lo ? t1 : ypk[4+j2];     // tile1 K-step0
        }
        uint32 t8 = (uint32)__builtin_amdgcn_ds_bpermute(srcT1, (int)ypk[8]);
        uint32 t9 = (uint32)__builtin_amdgcn_ds_bpermute(srcT1, (int)ypk[9]);
        uint32x4 f00v = {f00[0], f00[1], f00[2], f00[3]};
        uint32x4 f10v = {f10[0], f10[1], f10[2], f10[3]};
        uint32x4 f01v = {lo ? ypk[8] : 0u, lo ? ypk[9] : 0u, 0u, 0u};  // tile0 K-step1
        uint32x4 f11v = {lo ? t8 : 0u,     lo ? t9 : 0u,     0u, 0u};  // tile1 K-step1

        half8 A0 = cf ? A01 : A00;
        half8 A1 = cf ? A11 : A10;

        f32x16 c0 = __builtin_amdgcn_mfma_f32_32x32x16_f16(A0, __builtin_bit_cast(half8, f00v), hbacc, 0, 0, 0);
        c0 = __builtin_amdgcn_mfma_f32_32x32x16_f16(A1, __builtin_bit_cast(half8, f01v), c0, 0, 0, 0);
        f32x16 c1 = __builtin_amdgcn_mfma_f32_32x32x16_f16(A0, __builtin_bit_cast(half8, f10v), hbacc, 0, 0, 0);
        c1 = __builtin_amdgcn_mfma_f32_32x32x16_f16(A1, __builtin_bit_cast(half8, f11v), c1, 0, 0, 0);

        #pragma unroll
        for (int r = 0; r < 12; ++r) qA = fmaf(mwv[r], fmaxf(c0[r], 0.f), qA);
        #pragma unroll
        for (int r = 0; r < 12; ++r) qB = fmaf(mwv[r], fmaxf(c1[r], 0.f), qB);
    }

    // combine lane halves
    float sA = __builtin_bit_cast(float, __builtin_amdgcn_ds_bpermute(srcX, __builtin_bit_cast(int, qA)));
    float sB = __builtin_bit_cast(float, __builtin_amdgcn_ds_bpermute(srcX, __builtin_bit_cast(int, qB)));
    float qv = (lo ? qA + sA : qB + sB) + 7.f * ws[WS_MB];
    if (b < B) out[(size_t)b*8 + p] = qv;
}

extern "C" void kernel_launch(void* const* d_in, const int* in_sizes, int n_in,
                              void* d_out, int out_size, void* d_ws, size_t ws_size,
                              hipStream_t stream) {
    const float* states       = (const float*)d_in[0];
    const int*   p2m          = (const int*)  d_in[1];
    const int*   comp_mask    = (const int*)  d_in[3];
    const float* p_emb        = (const float*)d_in[4];
    const float* d_W          = (const float*)d_in[5];
    const float* d_b          = (const float*)d_in[6];
    const float* lane_W       = (const float*)d_in[7];
    const float* lane_b       = (const float*)d_in[8];
    const float* lane_conv_W  = (const float*)d_in[9];
    const float* lane_conv_b  = (const float*)d_in[10];
    const float* rel_emb      = (const float*)d_in[11];
    const float* rel_conv_W   = (const float*)d_in[12];
    const float* rel_conv_b   = (const float*)d_in[13];
    const float* hid_W        = (const float*)d_in[14];
    const float* hid_b        = (const float*)d_in[15];
    const float* merge_W      = (const float*)d_in[16];
    const float* merge_b      = (const float*)d_in[17];
    float* out = (float*)d_out;
    float* ws  = (float*)d_ws;

    frap_setup<<<1, 256, 0, stream>>>(p2m, comp_mask, p_emb, d_W, d_b, lane_W, lane_b,
        lane_conv_W, lane_conv_b, rel_emb, rel_conv_W, rel_conv_b, hid_W, hid_b,
        merge_W, merge_b, ws);

    int B = in_sizes[0] / 13;
    int grid = (B + 63) / 64;
    frap_main<<<grid, 512, 0, stream>>>(states, comp_mask, ws, out, B);
}